// Round 8
// baseline (1408.400 us; speedup 1.0000x reference)
//
#include <hip/hip_runtime.h>

// LSTM B=2048,T=512,I=5,H=128 + linear -> [B,1], fp32 in/out.
// Round 8: ping-pong wave specialization. r6's 1970cyc step = serialized
// phases (MFMA 776 + cell-VALU 790 strictly alternate per wave; the pipes can
// co-issue per m114 but lockstep barriers prevent it; r7 proved more waves in
// lockstep don't help). Now: grid=128, BT=16, NT=1024. Waves 0-7 = half A
// (batches 0-7), waves 8-15 = half B (batches 8-15), each running the proven
// r6 step on its own hbuf rows, phase-shifted by half a step:
//   phase1 [A:MFMA(k) || B:cell(k-1)]  barrier
//   phase2 [A:cell(k) || B:MFMA(k)]    barrier
// Every phase: 2 MFMA-waves + 2 cell-waves per SIMD -> MFMA and VALU co-issue.
// Each half's h reads/writes are barrier-separated -> single-buffered hbuf.
// Expected ~2x: per-t = 2 phases x ~(776+overhead) for 16 batches.
// VGPR must fit 128 (NT=1024 cap): ds_reads split in 2 groups to shrink
// live ranges; acc persists across one barrier for B waves.

#define HH 128
#define II 5
#define TT 512
#define BT 16
#define NT 1024
#define KS 136             // hbuf row stride in f16
#define XT (TT * 8 + 8)    // xs per-batch stride in f16

typedef __attribute__((ext_vector_type(8))) _Float16 half8;
typedef __attribute__((ext_vector_type(4))) float f32x4;

#define SIG(u) __builtin_amdgcn_rcpf(1.0f + __builtin_amdgcn_exp2f(u))

// MFMA phase: this wave's 4 gate-tiles (cols hcol) for its half's 8 batches.
// Reads split in two groups to cap VGPR live range.
#define MFMA_PHASE() {                                                          \
    if (xmask) ax = *reinterpret_cast<const half8*>(xcur);                      \
    if (nmask) {                                                                \
        ah0 = *reinterpret_cast<const half8*>(hrd);                             \
        ah1 = *reinterpret_cast<const half8*>(hrd + 32);                        \
    }                                                                           \
    _Pragma("unroll")                                                           \
    for (int g = 0; g < 4; ++g) {                                               \
        acc[g] = __builtin_amdgcn_mfma_f32_16x16x32_f16(ax,  wf[g][4], zero4,  0, 0, 0); \
        acc[g] = __builtin_amdgcn_mfma_f32_16x16x32_f16(ah0, wf[g][0], acc[g], 0, 0, 0); \
    }                                                                           \
    if (nmask) {                                                                \
        ah2 = *reinterpret_cast<const half8*>(hrd + 64);                        \
        ah3 = *reinterpret_cast<const half8*>(hrd + 96);                        \
    }                                                                           \
    _Pragma("unroll")                                                           \
    for (int g = 0; g < 4; ++g) {                                               \
        acc[g] = __builtin_amdgcn_mfma_f32_16x16x32_f16(ah1, wf[g][1], acc[g], 0, 0, 0); \
        acc[g] = __builtin_amdgcn_mfma_f32_16x16x32_f16(ah2, wf[g][2], acc[g], 0, 0, 0); \
        acc[g] = __builtin_amdgcn_mfma_f32_16x16x32_f16(ah3, wf[g][3], acc[g], 0, 0, 0); \
    }                                                                           \
}

// Cell phase: consume acc (C-layout), 2 cells/lane via shfl_xor(32) (r6).
#define CELL_PHASE(LAST) {                                                      \
    float gate[4][2];                                                           \
    _Pragma("unroll")                                                           \
    for (int g = 0; g < 4; ++g) {                                               \
        float s2 = __shfl_xor(acc[g][2], 32, 64);                               \
        float s3 = __shfl_xor(acc[g][3], 32, 64);                               \
        gate[g][0] = lo ? acc[g][0] : s2;                                       \
        gate[g][1] = lo ? acc[g][1] : s3;                                       \
    }                                                                           \
    float iv = SIG(gate[0][0]);                                                 \
    float fv = SIG(gate[1][0]);                                                 \
    float gv = 1.0f - 2.0f * SIG(gate[2][0]);                                   \
    float ov = SIG(gate[3][0]);                                                 \
    cc0 = fv * cc0 + iv * gv;                                                   \
    float hv0 = ov * (1.0f - 2.0f * SIG(2.88539008f * cc0));                    \
    iv = SIG(gate[0][1]);                                                       \
    fv = SIG(gate[1][1]);                                                       \
    gv = 1.0f - 2.0f * SIG(gate[2][1]);                                         \
    ov = SIG(gate[3][1]);                                                       \
    cc1 = fv * cc1 + iv * gv;                                                   \
    float hv1 = ov * (1.0f - 2.0f * SIG(2.88539008f * cc1));                    \
    if (LAST) {                                                                 \
        hsc[hrow0][hcol] = hv0; hsc[hrow0 + 1][hcol] = hv1;                     \
    } else {                                                                    \
        hwr[0]  = (_Float16)hv0;                                                \
        hwr[KS] = (_Float16)hv1;                                                \
    }                                                                           \
}

__global__ __launch_bounds__(NT)
void lstm_r8(const float* __restrict__ x,      // [B,T,I]
             const float* __restrict__ W_ih,   // [4H,I]
             const float* __restrict__ W_hh,   // [4H,H]
             const float* __restrict__ b_ih,   // [4H]
             const float* __restrict__ b_hh,   // [4H]
             const float* __restrict__ W_lin,  // [H]
             const float* __restrict__ b_lin,  // [1]
             float* __restrict__ out,          // [B]
             int B)
{
    __shared__ __align__(16) _Float16 hbuf[BT][KS];   // 4.3 KB, single-buffered
    __shared__ __align__(16) _Float16 xs[BT * XT];    // 131.3 KB staged x (f16)
    __shared__ float hsc[BT][HH + 4];                 // 8.4 KB final fp32 h

    const int tid  = threadIdx.x;
    const int b0   = blockIdx.x * BT;
    const int lane = tid & 63;
    const int w    = tid >> 6;        // 0..15
    const bool isA = (w < 8);
    const int half = isA ? 0 : 1;
    const int wg   = w & 7;           // col group (same for both halves)
    const int n    = lane & 15;       // A row (batch within half) / D col
    const int q    = lane >> 4;
    const int q8   = q * 8;
    const int hcol = wg * 16 + n;     // this wave's gate columns

    // ---- W frags, f16, B-layout, activation scale folded --------------------
    // k<128: W_hh; 128..132: W_ih; 133: bias; rest 0.
    half8 wf[4][5];
    #pragma unroll
    for (int g = 0; g < 4; ++g) {
        const float sc = (g == 2) ? 2.88539008f : -1.44269504f;
        const int j = g * HH + hcol;
        #pragma unroll
        for (int kc = 0; kc < 4; ++kc) {
            const float* p = W_hh + (size_t)j * HH + kc * 32 + q8;
            #pragma unroll
            for (int e = 0; e < 8; ++e) wf[g][kc][e] = (_Float16)(p[e] * sc);
        }
        #pragma unroll
        for (int e = 0; e < 8; ++e) {
            const int k = q8 + e;
            float v = 0.0f;
            if (k < II)       v = W_ih[j * II + k];
            else if (k == II) v = b_ih[j] + b_hh[j];
            wf[g][4][e] = (_Float16)(v * sc);
        }
    }

    // ---- zero LDS -----------------------------------------------------------
    for (int idx = tid; idx < BT * KS; idx += NT)
        (&hbuf[0][0])[idx] = (_Float16)0.0f;
    for (int idx = tid; idx < BT * XT; idx += NT)
        xs[idx] = (_Float16)0.0f;
    __syncthreads();

    // ---- stage x (f16) + constant-1.0 bias column in slot 5 -----------------
    {
        const int lb = tid & 63, bb = tid >> 6;     // 64 threads per batch
        if (b0 + bb < B) {
            const float* xb = x + (size_t)(b0 + bb) * TT * II;
            for (int e = lb * 4; e < TT * II; e += 256) {
                float4 v = *reinterpret_cast<const float4*>(xb + e);
                float vv[4] = {v.x, v.y, v.z, v.w};
                #pragma unroll
                for (int u = 0; u < 4; ++u) {
                    const int ee = e + u;
                    xs[bb * XT + (ee / 5) * 8 + (ee % 5)] = (_Float16)vv[u];
                }
            }
        }
        for (int s = tid; s < BT * TT; s += NT)
            xs[(s >> 9) * XT + (s & 511) * 8 + 5] = (_Float16)1.0f;
    }
    __syncthreads();

    // ---- loop-invariant state ----------------------------------------------
    const int m0    = (q & 1) * 4 + (q >> 1) * 2;   // cell rows m0, m0+1 (in half)
    const int hrow0 = half * 8 + m0;
    float cc0 = 0.f, cc1 = 0.f;
    const f32x4 zero4 = {0.f, 0.f, 0.f, 0.f};
    const bool nmask = (n < 8);
    const bool xmask = (q == 0) && nmask;
    const bool lo    = (lane < 32);
    const _Float16* hrd  = &hbuf[half * 8 + (n & 7)][0] + q8;
    _Float16*       hwr  = &hbuf[hrow0][0] + hcol;
    const _Float16* xcur = &xs[(half * 8 + (n & 7)) * XT];   // +8 per t

    // persistent A-frags; masked lanes keep zeros forever
    half8 ax, ah0, ah1, ah2, ah3;
    #pragma unroll
    for (int e = 0; e < 8; ++e) ax[e] = (_Float16)0.0f;
    ah0 = ax; ah1 = ax; ah2 = ax; ah3 = ax;
    f32x4 acc[4];                       // persists across one barrier (B waves)

    // ---- ping-pong main loop -----------------------------------------------
    // k=0 peel: B has no cell(-1)
    if (isA) { MFMA_PHASE(); }
    __syncthreads();
    if (isA) { CELL_PHASE(false); } else { MFMA_PHASE(); }
    __syncthreads();
    xcur += 8;

    #pragma unroll 1
    for (int k = 1; k < TT - 1; ++k) {
        if (isA) { MFMA_PHASE(); } else { CELL_PHASE(false); }
        __syncthreads();
        if (isA) { CELL_PHASE(false); } else { MFMA_PHASE(); }
        __syncthreads();
        xcur += 8;
    }

    // k = TT-1 peel: A's last cell -> hsc; B trails by half a step
    if (isA) { MFMA_PHASE(); } else { CELL_PHASE(false); }
    __syncthreads();
    if (isA) { CELL_PHASE(true); } else { MFMA_PHASE(); }
    __syncthreads();
    if (!isA) { CELL_PHASE(true); }
    __syncthreads();

    // ---- epilogue: out[b0+w] = hsc[w,:] . W_lin + b_lin ---------------------
    float p = hsc[w][lane] * W_lin[lane] + hsc[w][lane + 64] * W_lin[lane + 64];
    #pragma unroll
    for (int off = 32; off > 0; off >>= 1) p += __shfl_down(p, off, 64);
    if (lane == 0 && (b0 + w) < B) out[b0 + w] = p + b_lin[0];
}

extern "C" void kernel_launch(void* const* d_in, const int* in_sizes, int n_in,
                              void* d_out, int out_size, void* d_ws, size_t ws_size,
                              hipStream_t stream) {
    const float* x     = (const float*)d_in[0];
    const float* W_ih  = (const float*)d_in[1];
    const float* W_hh  = (const float*)d_in[2];
    const float* b_ih  = (const float*)d_in[3];
    const float* b_hh  = (const float*)d_in[4];
    const float* W_lin = (const float*)d_in[5];
    const float* b_lin = (const float*)d_in[6];
    float* out = (float*)d_out;

    const int B = in_sizes[0] / (TT * II);          // 2048
    const int grid = (B + BT - 1) / BT;             // 128 blocks
    lstm_r8<<<grid, NT, 0, stream>>>(x, W_ih, W_hh, b_ih, b_hh,
                                     W_lin, b_lin, out, B);
}

// Round 9
// 720.902 us; speedup vs baseline: 1.9537x; 1.9537x over previous
//
#include <hip/hip_runtime.h>

// LSTM B=2048,T=512,I=5,H=128 + linear -> [B,1], fp32 in/out.
// Round 9 = round 8 ping-pong, allocation fixed. r8 failed because without
// amdgpu_waves_per_eu the compiler targeted 64 VGPRs and spilled the 80-VGPR
// wf array to scratch (WRITE_SIZE 47MB). Fixes:
//   (1) amdgpu_waves_per_eu(4,4): 16 waves/CU -> 128-VGPR budget, no spill.
//   (2) unconditional ds_reads via a zeroed LDS row (zrow): masked lanes read
//       zeros at a wave-shared broadcast address instead of keeping 20 pinned
//       zero VGPRs + exec-mask churn alive across the loop.
// Structure (correctness-verified in r8): grid=128, BT=16, NT=1024. Waves 0-7
// = batches 0-7 (half A), waves 8-15 = batches 8-15 (half B) - two independent
// 8-batch LSTMs phase-shifted by half a step:
//   phase1 [A:MFMA(k) || B:cell(k-1)]  barrier
//   phase2 [A:cell(k) || B:MFMA(k)]    barrier
// -> every phase has 2 MFMA-issuing + 2 VALU-issuing waves per SIMD; the two
// pipes co-issue (m114) instead of r6's strict 776+790 serialization.

#define HH 128
#define II 5
#define TT 512
#define BT 16
#define NT 1024
#define KS 136             // hbuf row stride in f16
#define XT (TT * 8 + 8)    // xs per-batch stride in f16

typedef __attribute__((ext_vector_type(8))) _Float16 half8;
typedef __attribute__((ext_vector_type(4))) float f32x4;

#define SIG(u) __builtin_amdgcn_rcpf(1.0f + __builtin_amdgcn_exp2f(u))

// MFMA phase: this wave's 4 gate-tiles (cols hcol) for its half's 8 batches.
// All loads unconditional; masked lanes' pointers target zeroed LDS (zrow).
#define MFMA_PHASE() {                                                          \
    ax  = *reinterpret_cast<const half8*>(xcur);                                \
    ah0 = *reinterpret_cast<const half8*>(hrd);                                 \
    ah1 = *reinterpret_cast<const half8*>(hrd + 32);                            \
    _Pragma("unroll")                                                           \
    for (int g = 0; g < 4; ++g) {                                               \
        acc[g] = __builtin_amdgcn_mfma_f32_16x16x32_f16(ax,  wf[g][4], zero4,  0, 0, 0); \
        acc[g] = __builtin_amdgcn_mfma_f32_16x16x32_f16(ah0, wf[g][0], acc[g], 0, 0, 0); \
    }                                                                           \
    ah2 = *reinterpret_cast<const half8*>(hrd + 64);                            \
    ah3 = *reinterpret_cast<const half8*>(hrd + 96);                            \
    _Pragma("unroll")                                                           \
    for (int g = 0; g < 4; ++g) {                                               \
        acc[g] = __builtin_amdgcn_mfma_f32_16x16x32_f16(ah1, wf[g][1], acc[g], 0, 0, 0); \
        acc[g] = __builtin_amdgcn_mfma_f32_16x16x32_f16(ah2, wf[g][2], acc[g], 0, 0, 0); \
        acc[g] = __builtin_amdgcn_mfma_f32_16x16x32_f16(ah3, wf[g][3], acc[g], 0, 0, 0); \
    }                                                                           \
}

// Cell phase: consume acc (C-layout), 2 cells/lane via shfl_xor(32).
#define CELL_PHASE(LAST) {                                                      \
    float gate[4][2];                                                           \
    _Pragma("unroll")                                                           \
    for (int g = 0; g < 4; ++g) {                                               \
        float s2 = __shfl_xor(acc[g][2], 32, 64);                               \
        float s3 = __shfl_xor(acc[g][3], 32, 64);                               \
        gate[g][0] = lo ? acc[g][0] : s2;                                       \
        gate[g][1] = lo ? acc[g][1] : s3;                                       \
    }                                                                           \
    float iv = SIG(gate[0][0]);                                                 \
    float fv = SIG(gate[1][0]);                                                 \
    float gv = 1.0f - 2.0f * SIG(gate[2][0]);                                   \
    float ov = SIG(gate[3][0]);                                                 \
    cc0 = fv * cc0 + iv * gv;                                                   \
    float hv0 = ov * (1.0f - 2.0f * SIG(2.88539008f * cc0));                    \
    iv = SIG(gate[0][1]);                                                       \
    fv = SIG(gate[1][1]);                                                       \
    gv = 1.0f - 2.0f * SIG(gate[2][1]);                                         \
    ov = SIG(gate[3][1]);                                                       \
    cc1 = fv * cc1 + iv * gv;                                                   \
    float hv1 = ov * (1.0f - 2.0f * SIG(2.88539008f * cc1));                    \
    if (LAST) {                                                                 \
        hsc[hrow0][hcol] = hv0; hsc[hrow0 + 1][hcol] = hv1;                     \
    } else {                                                                    \
        hwr[0]  = (_Float16)hv0;                                                \
        hwr[KS] = (_Float16)hv1;                                                \
    }                                                                           \
}

__global__ __launch_bounds__(NT)
__attribute__((amdgpu_waves_per_eu(4, 4)))   // 128-VGPR budget: r8 spill fix
void lstm_r9(const float* __restrict__ x,      // [B,T,I]
             const float* __restrict__ W_ih,   // [4H,I]
             const float* __restrict__ W_hh,   // [4H,H]
             const float* __restrict__ b_ih,   // [4H]
             const float* __restrict__ b_hh,   // [4H]
             const float* __restrict__ W_lin,  // [H]
             const float* __restrict__ b_lin,  // [1]
             float* __restrict__ out,          // [B]
             int B)
{
    __shared__ __align__(16) _Float16 hbuf[BT][KS];   // 4.3 KB, single-buffered
    __shared__ __align__(16) _Float16 zrow[KS];       // all-zero row for masked lanes
    __shared__ __align__(16) _Float16 xs[BT * XT];    // 131.3 KB staged x (f16)
    __shared__ float hsc[BT][HH + 4];                 // 8.4 KB final fp32 h

    const int tid  = threadIdx.x;
    const int b0   = blockIdx.x * BT;
    const int lane = tid & 63;
    const int w    = tid >> 6;        // 0..15
    const bool isA = (w < 8);
    const int half = isA ? 0 : 1;
    const int wg   = w & 7;           // col group
    const int n    = lane & 15;       // A row (batch within half) / D col
    const int q    = lane >> 4;
    const int q8   = q * 8;
    const int hcol = wg * 16 + n;     // this wave's gate columns

    // ---- W frags, f16, B-layout, activation scale folded --------------------
    half8 wf[4][5];
    #pragma unroll
    for (int g = 0; g < 4; ++g) {
        const float sc = (g == 2) ? 2.88539008f : -1.44269504f;
        const int j = g * HH + hcol;
        #pragma unroll
        for (int kc = 0; kc < 4; ++kc) {
            const float* p = W_hh + (size_t)j * HH + kc * 32 + q8;
            #pragma unroll
            for (int e = 0; e < 8; ++e) wf[g][kc][e] = (_Float16)(p[e] * sc);
        }
        #pragma unroll
        for (int e = 0; e < 8; ++e) {
            const int k = q8 + e;
            float v = 0.0f;
            if (k < II)       v = W_ih[j * II + k];
            else if (k == II) v = b_ih[j] + b_hh[j];
            wf[g][4][e] = (_Float16)(v * sc);
        }
    }

    // ---- zero LDS -----------------------------------------------------------
    for (int idx = tid; idx < BT * KS; idx += NT)
        (&hbuf[0][0])[idx] = (_Float16)0.0f;
    if (tid < KS) zrow[tid] = (_Float16)0.0f;
    for (int idx = tid; idx < BT * XT; idx += NT)
        xs[idx] = (_Float16)0.0f;
    __syncthreads();

    // ---- stage x (f16) + constant-1.0 bias column in slot 5 -----------------
    {
        const int lb = tid & 63, bb = tid >> 6;     // 64 threads per batch
        if (b0 + bb < B) {
            const float* xb = x + (size_t)(b0 + bb) * TT * II;
            for (int e = lb * 4; e < TT * II; e += 256) {
                float4 v = *reinterpret_cast<const float4*>(xb + e);
                float vv[4] = {v.x, v.y, v.z, v.w};
                #pragma unroll
                for (int u = 0; u < 4; ++u) {
                    const int ee = e + u;
                    xs[bb * XT + (ee / 5) * 8 + (ee % 5)] = (_Float16)vv[u];
                }
            }
        }
        for (int s = tid; s < BT * TT; s += NT)
            xs[(s >> 9) * XT + (s & 511) * 8 + 5] = (_Float16)1.0f;
    }
    __syncthreads();

    // ---- loop-invariant state ----------------------------------------------
    const int m0    = (q & 1) * 4 + (q >> 1) * 2;   // cell rows m0, m0+1 (in half)
    const int hrow0 = half * 8 + m0;
    float cc0 = 0.f, cc1 = 0.f;
    const f32x4 zero4 = {0.f, 0.f, 0.f, 0.f};
    const bool lo = (lane < 32);
    // masked lanes read zeros from zrow at a broadcast address (conflict-free)
    const bool hact = (n < 8);
    const bool xact = hact && (q == 0);
    const _Float16* hrd  = hact ? (&hbuf[half * 8 + n][0] + q8) : (&zrow[0] + q8);
    const _Float16* xcur = xact ? &xs[(half * 8 + n) * XT] : &zrow[0];
    const int       xinc = xact ? 8 : 0;            // inactive lanes stay in zrow
    _Float16*       hwr  = &hbuf[hrow0][0] + hcol;

    half8 ax, ah0, ah1, ah2, ah3;
    f32x4 acc[4];                       // persists across one barrier per half-step

    // ---- ping-pong main loop -----------------------------------------------
    // k=0 peel: B has no cell(-1)
    if (isA) { MFMA_PHASE(); }
    __syncthreads();
    if (isA) { CELL_PHASE(false); } else { MFMA_PHASE(); }
    __syncthreads();
    xcur += xinc;

    #pragma unroll 1
    for (int k = 1; k < TT - 1; ++k) {
        if (isA) { MFMA_PHASE(); } else { CELL_PHASE(false); }
        __syncthreads();
        if (isA) { CELL_PHASE(false); } else { MFMA_PHASE(); }
        __syncthreads();
        xcur += xinc;
    }

    // k = TT-1 peel: A's last cell -> hsc; B trails by half a step
    if (isA) { MFMA_PHASE(); } else { CELL_PHASE(false); }
    __syncthreads();
    if (isA) { CELL_PHASE(true); } else { MFMA_PHASE(); }
    __syncthreads();
    if (!isA) { CELL_PHASE(true); }
    __syncthreads();

    // ---- epilogue: out[b0+w] = hsc[w,:] . W_lin + b_lin ---------------------
    float p = hsc[w][lane] * W_lin[lane] + hsc[w][lane + 64] * W_lin[lane + 64];
    #pragma unroll
    for (int off = 32; off > 0; off >>= 1) p += __shfl_down(p, off, 64);
    if (lane == 0 && (b0 + w) < B) out[b0 + w] = p + b_lin[0];
}

extern "C" void kernel_launch(void* const* d_in, const int* in_sizes, int n_in,
                              void* d_out, int out_size, void* d_ws, size_t ws_size,
                              hipStream_t stream) {
    const float* x     = (const float*)d_in[0];
    const float* W_ih  = (const float*)d_in[1];
    const float* W_hh  = (const float*)d_in[2];
    const float* b_ih  = (const float*)d_in[3];
    const float* b_hh  = (const float*)d_in[4];
    const float* W_lin = (const float*)d_in[5];
    const float* b_lin = (const float*)d_in[6];
    float* out = (float*)d_out;

    const int B = in_sizes[0] / (TT * II);          // 2048
    const int grid = (B + BT - 1) / BT;             // 128 blocks
    lstm_r9<<<grid, NT, 0, stream>>>(x, W_ih, W_hh, b_ih, b_hh,
                                     W_lin, b_lin, out, B);
}

// Round 10
// 352.451 us; speedup vs baseline: 3.9960x; 2.0454x over previous
//
#include <hip/hip_runtime.h>

// LSTM B=2048,T=512,I=5,H=128 + linear -> [B,1], fp32 in/out.
// Round 10 = r6 structure (256 blocks x 8 batches, NT=512, proven 92-VGPR
// allocation) with the measured overheads cut:
//  (1) ROW PERMUTATION: h of batch b lives at A-row rho(b)=(b>>1)*4+(b&1)
//      ({0,1,4,5,8,9,12,13}); C/D rows q*4+{0,1} at quad q are then exactly
//      batches {2q,2q+1} -> every lane owns its 2 cells directly in
//      acc[g][0..1]. r6's shfl_xor+cndmask redistribute (8 bperm + 8 cndmask
//      + latency tail) is gone. Pad rows (==2,3 mod 4) are permanently zero
//      -> ALL A-frag h reads unconditional, no exec masks.
//  (2) ax SOFTWARE PIPELINE: xs is static; ax(t+1) ds_read issues right after
//      the MFMA phase of t, crosses the barrier in-register, latency hidden
//      under cell transcendentals.
//  (3) unchanged proven parts: f16 operands (absmax 4.9e-4), folded activation
//      scales in wf, bias as xs slot-5 constant-1.0 column, dbuf h + single
//      barrier/step, peeled last step, waves_per_eu(2,2) spill guard.
// r8/r9 lesson recorded: 1024-thread blocks pin the allocator at 64 VGPR
// (attribute ignored) -> spill; BT=16 also halves active CUs. Avoid both.

#define HH 128
#define II 5
#define TT 512
#define BT 8
#define NT 512
#define KS 136             // hbuf row stride in f16
#define XT (TT * 8 + 8)    // xs per-batch stride in f16
#define HB (16 * KS)       // hbuf buffer stride in f16 elems

typedef __attribute__((ext_vector_type(8))) _Float16 half8;
typedef __attribute__((ext_vector_type(4))) float f32x4;

#define SIG(u) __builtin_amdgcn_rcpf(1.0f + __builtin_amdgcn_exp2f(u))

// One timestep. PB = h read buffer (compile-time 0/1), LAST = peeled final.
#define STEP(PB, LAST) {                                                        \
    const _Float16* hp = hrd + (PB) * HB;                                       \
    ah0 = *reinterpret_cast<const half8*>(hp);                                  \
    ah1 = *reinterpret_cast<const half8*>(hp + 32);                             \
    ah2 = *reinterpret_cast<const half8*>(hp + 64);                             \
    ah3 = *reinterpret_cast<const half8*>(hp + 96);                             \
    f32x4 acc[4];                                                               \
    _Pragma("unroll")                                                           \
    for (int g = 0; g < 4; ++g) {                                               \
        acc[g] = __builtin_amdgcn_mfma_f32_16x16x32_f16(ax,  wf[g][4], zero4,  0, 0, 0); \
        acc[g] = __builtin_amdgcn_mfma_f32_16x16x32_f16(ah0, wf[g][0], acc[g], 0, 0, 0); \
        acc[g] = __builtin_amdgcn_mfma_f32_16x16x32_f16(ah1, wf[g][1], acc[g], 0, 0, 0); \
        acc[g] = __builtin_amdgcn_mfma_f32_16x16x32_f16(ah2, wf[g][2], acc[g], 0, 0, 0); \
        acc[g] = __builtin_amdgcn_mfma_f32_16x16x32_f16(ah3, wf[g][3], acc[g], 0, 0, 0); \
    }                                                                           \
    if (!(LAST)) {                      /* prefetch ax(t+1): static xs, no WAR */\
        xcur += xinc;                                                           \
        ax = *reinterpret_cast<const half8*>(xcur);                             \
    }                                                                           \
    float iv = SIG(acc[0][0]);                                                  \
    float fv = SIG(acc[1][0]);                                                  \
    float gv = 1.0f - 2.0f * SIG(acc[2][0]);                                    \
    float ov = SIG(acc[3][0]);                                                  \
    cc0 = fv * cc0 + iv * gv;                                                   \
    float hv0 = ov * (1.0f - 2.0f * SIG(2.88539008f * cc0));                    \
    iv = SIG(acc[0][1]);                                                        \
    fv = SIG(acc[1][1]);                                                        \
    gv = 1.0f - 2.0f * SIG(acc[2][1]);                                          \
    ov = SIG(acc[3][1]);                                                        \
    cc1 = fv * cc1 + iv * gv;                                                   \
    float hv1 = ov * (1.0f - 2.0f * SIG(2.88539008f * cc1));                    \
    if (LAST) {                                                                 \
        hsc[bcell][hcol] = hv0; hsc[bcell + 1][hcol] = hv1;                     \
    } else {                                                                    \
        _Float16* wp = hwr + ((PB) ^ 1) * HB;                                   \
        wp[0]  = (_Float16)hv0;                                                 \
        wp[KS] = (_Float16)hv1;                                                 \
    }                                                                           \
    __syncthreads();                                                            \
}

__global__ __launch_bounds__(NT)
__attribute__((amdgpu_waves_per_eu(2, 2)))   // 256-VGPR budget: spill guard
void lstm_r10(const float* __restrict__ x,      // [B,T,I]
              const float* __restrict__ W_ih,   // [4H,I]
              const float* __restrict__ W_hh,   // [4H,H]
              const float* __restrict__ b_ih,   // [4H]
              const float* __restrict__ b_hh,   // [4H]
              const float* __restrict__ W_lin,  // [H]
              const float* __restrict__ b_lin,  // [1]
              float* __restrict__ out,          // [B]
              int B)
{
    __shared__ __align__(16) _Float16 hbuf[2][16][KS];  // 8.7 KB; rows 2,3 mod 4 stay 0
    __shared__ __align__(16) _Float16 zrow[KS];         // zeros for invalid x lanes
    __shared__ __align__(16) _Float16 xs[BT * XT];      // 65.7 KB staged x (f16)
    __shared__ float hsc[BT][HH + 4];                   // final fp32 h

    const int tid  = threadIdx.x;
    const int b0   = blockIdx.x * BT;
    const int lane = tid & 63;
    const int w    = tid >> 6;        // 0..7 -> col group
    const int n    = lane & 15;       // A row index / D col
    const int q    = lane >> 4;
    const int q8   = q * 8;
    const int hcol = w * 16 + n;      // this wave's gate columns

    // ---- W frags, f16, B-layout (lane holds W^T[k=q8+e][col n]), scaled -----
    half8 wf[4][5];
    #pragma unroll
    for (int g = 0; g < 4; ++g) {
        const float sc = (g == 2) ? 2.88539008f : -1.44269504f;
        const int j = g * HH + hcol;
        #pragma unroll
        for (int kc = 0; kc < 4; ++kc) {
            const float* p = W_hh + (size_t)j * HH + kc * 32 + q8;
            #pragma unroll
            for (int e = 0; e < 8; ++e) wf[g][kc][e] = (_Float16)(p[e] * sc);
        }
        #pragma unroll
        for (int e = 0; e < 8; ++e) {
            const int k = q8 + e;
            float v = 0.0f;
            if (k < II)       v = W_ih[j * II + k];
            else if (k == II) v = b_ih[j] + b_hh[j];
            wf[g][4][e] = (_Float16)(v * sc);
        }
    }

    // ---- zero LDS -----------------------------------------------------------
    for (int idx = tid; idx < 2 * 16 * KS; idx += NT)
        (&hbuf[0][0][0])[idx] = (_Float16)0.0f;
    if (tid < KS) zrow[tid] = (_Float16)0.0f;
    for (int idx = tid; idx < BT * XT; idx += NT)
        xs[idx] = (_Float16)0.0f;
    __syncthreads();

    // ---- stage x (f16) + constant-1.0 bias column in slot 5 -----------------
    {
        const int lb = tid & 63, bb = tid >> 6;     // 64 threads per batch
        if (b0 + bb < B) {
            const float* xb = x + (size_t)(b0 + bb) * TT * II;
            for (int e = lb * 4; e < TT * II; e += 256) {
                float4 v = *reinterpret_cast<const float4*>(xb + e);
                float vv[4] = {v.x, v.y, v.z, v.w};
                #pragma unroll
                for (int u = 0; u < 4; ++u) {
                    const int ee = e + u;
                    xs[bb * XT + (ee / 5) * 8 + (ee % 5)] = (_Float16)vv[u];
                }
            }
        }
        for (int s = tid; s < BT * TT; s += NT)
            xs[(s >> 9) * XT + (s & 511) * 8 + 5] = (_Float16)1.0f;
    }
    __syncthreads();

    // ---- loop-invariant state ----------------------------------------------
    // Row permutation: batch b -> A-row rho(b) = (b>>1)*4 + (b&1).
    // A-row n is real iff (n&2)==0; its batch = (n>>2)*2 + (n&1).
    // C/D rows q*4+{0,1} = batches {2q, 2q+1} -> direct cell ownership.
    const int bcell = 2 * q;                        // this lane's batches: bcell, bcell+1
    float cc0 = 0.f, cc1 = 0.f;
    const f32x4 zero4 = {0.f, 0.f, 0.f, 0.f};
    const bool xreal = ((n & 2) == 0);
    const int  bofn  = (n >> 2) * 2 + (n & 1);      // batch carried by A-row n
    const _Float16* hrd  = &hbuf[0][n][0] + q8;     // unconditional (pad rows = 0)
    _Float16*       hwr  = &hbuf[0][q * 4][0] + hcol;  // rows q*4, q*4+1 (+KS)
    const _Float16* xcur = xreal ? &xs[bofn * XT] : &zrow[0];
    const int       xinc = xreal ? 8 : 0;

    half8 ax, ah0, ah1, ah2, ah3;
    ax = *reinterpret_cast<const half8*>(xcur);     // t=0 preload

    #pragma unroll 1
    for (int k = 0; k < (TT - 2) / 2; ++k) {
        STEP(0, false);
        STEP(1, false);
    }
    STEP(0, false);     // t = 510
    STEP(1, true);      // t = 511, peeled: fp32 hsc write, no prefetch

    // ---- epilogue: out[b0+w] = hsc[w,:] . W_lin + b_lin ---------------------
    float p = hsc[w][lane] * W_lin[lane] + hsc[w][lane + 64] * W_lin[lane + 64];
    #pragma unroll
    for (int off = 32; off > 0; off >>= 1) p += __shfl_down(p, off, 64);
    if (lane == 0 && (b0 + w) < B) out[b0 + w] = p + b_lin[0];
}

extern "C" void kernel_launch(void* const* d_in, const int* in_sizes, int n_in,
                              void* d_out, int out_size, void* d_ws, size_t ws_size,
                              hipStream_t stream) {
    const float* x     = (const float*)d_in[0];
    const float* W_ih  = (const float*)d_in[1];
    const float* W_hh  = (const float*)d_in[2];
    const float* b_ih  = (const float*)d_in[3];
    const float* b_hh  = (const float*)d_in[4];
    const float* W_lin = (const float*)d_in[5];
    const float* b_lin = (const float*)d_in[6];
    float* out = (float*)d_out;

    const int B = in_sizes[0] / (TT * II);          // 2048
    const int grid = (B + BT - 1) / BT;             // 256 blocks, 1 per CU
    lstm_r10<<<grid, NT, 0, stream>>>(x, W_ih, W_hh, b_ih, b_hh,
                                      W_lin, b_lin, out, B);
}